// Round 6
// baseline (321.311 us; speedup 1.0000x reference)
//
#include <hip/hip_runtime.h>

#define N_VERT 35709
#define N_FACE 70789
#define NB 32
#define M3 (3*N_VERT)          // 107127
#define V4 ((size_t)N_VERT*4)  // fs32 per-batch stride (floats)

typedef _Float16 h4 __attribute__((ext_vector_type(4)));
typedef float vf4 __attribute__((ext_vector_type(4)));

// ---- workspace layout (BYTE offsets) ----
#define WSB_FS32 ((size_t)0)                          // [32][N_VERT][4] f32
#define WSB_FS16 (WSB_FS32 + (size_t)NB*V4*4)         // [N_VERT][32] h4
#define WSB_FN16 (WSB_FS16 + (size_t)N_VERT*NB*8)     // [N_FACE+1][32] h4
#define WSB_CPAD (WSB_FN16 + (size_t)(N_FACE+1)*NB*8) // [32][256] f32
#define WSB_ROT  (WSB_CPAD + (size_t)NB*256*4)        // [32][9] f32
#define WSB_TRE  (WSB_ROT + (size_t)NB*9*4)           // [32][3] f32
#define WSB_G    (WSB_TRE + (size_t)NB*3*4)           // [32][27] f32
#define WSB_MEAN (WSB_G + (size_t)NB*27*4)            // [3] f32

// ---- output layout (float offsets) ----
#define FC_OFF  ((size_t)0)
#define LM_OFF  ((size_t)NB*M3)
#define FST_OFF (LM_OFF + (size_t)NB*68*2)

// ---- SH constants ----
#define A0C0 0.88622692545275801f
#define A1C1 1.77245385090551603f
#define A2C2 2.42703239430f
#define Y6C  0.70062393935f
#define Y8C  1.21351619715f

// ======================= Stage A1: meanshape partial sums =======================
__global__ void __launch_bounds__(256) face3d_stageA1(
    const float* __restrict__ ms, float* __restrict__ mean) {
  float s0=0.f, s1=0.f, s2=0.f;
  for (int v = blockIdx.x*256 + threadIdx.x; v < N_VERT; v += gridDim.x*256) {
    s0 += ms[3*v+0]; s1 += ms[3*v+1]; s2 += ms[3*v+2];
  }
  #pragma unroll
  for (int off = 32; off > 0; off >>= 1) {
    s0 += __shfl_down(s0, off);
    s1 += __shfl_down(s1, off);
    s2 += __shfl_down(s2, off);
  }
  if ((threadIdx.x & 63) == 0) {
    atomicAdd(&mean[0], s0);
    atomicAdd(&mean[1], s1);
    atomicAdd(&mean[2], s2);
  }
}

// ======================= Stage A2: per-batch constants =======================
__global__ void __launch_bounds__(256) face3d_stageA2(
    const float* __restrict__ coeff, const float* __restrict__ mean,
    float* __restrict__ cpad, float* __restrict__ rotW,
    float* __restrict__ treW, float* __restrict__ gW) {
  int t = threadIdx.x;
  float m0 = mean[0]*(1.0f/N_VERT);
  float m1 = mean[1]*(1.0f/N_VERT);
  float m2 = mean[2]*(1.0f/N_VERT);
  for (int idx = t; idx < NB*256; idx += 256) {
    int b = idx >> 8, k = idx & 255;
    cpad[idx] = (k < 244) ? coeff[b*277 + k] : 0.0f;
  }
  for (int idx = t; idx < NB*27; idx += 256) {
    int b = idx / 27, k = idx - b*27;
    gW[idx] = coeff[b*277 + 247 + k] + (((k % 9) == 0) ? 0.8f : 0.0f);
  }
  if (t < NB) {
    int b = t;
    float ax = coeff[b*277+244], ay = coeff[b*277+245], az = coeff[b*277+246];
    float cx=cosf(ax), sx=sinf(ax);
    float cy=cosf(ay), sy=sinf(ay);
    float cz=cosf(az), sz=sinf(az);
    float T00=cz*cy, T01=-sz, T02=cz*sy;
    float T10=sz*cy, T11=cz,  T12=sz*sy;
    float T20=-sy,   T21=0.f, T22=cy;
    float R[3][3];
    R[0][0]=T00; R[0][1]=T01*cx+T02*sx; R[0][2]=-T01*sx+T02*cx;
    R[1][0]=T10; R[1][1]=T11*cx+T12*sx; R[1][2]=-T11*sx+T12*cx;
    R[2][0]=T20; R[2][1]=T21*cx+T22*sx; R[2][2]=-T21*sx+T22*cx;
    float rot[3][3];
    #pragma unroll
    for (int c=0;c<3;c++)
      #pragma unroll
      for (int j=0;j<3;j++)
        rot[c][j] = R[j][c];
    #pragma unroll
    for (int c=0;c<3;c++)
      #pragma unroll
      for (int j=0;j<3;j++)
        rotW[b*9 + c*3 + j] = rot[c][j];
    #pragma unroll
    for (int j=0;j<3;j++)
      treW[b*3 + j] = coeff[b*277+274+j]
        - (m0*rot[0][j] + m1*rot[1][j] + m2*rot[2][j]);
  }
}

// ======================= Stage B: GEMMs (8 rows x 2 batches / thread) =======================
// W LDS layout: [32 b][65 float4] (pad 64->65). bg = t&15 -> batches 2bg, 2bg+1.
// 16 adjacent lanes share A addresses (same-address dedupe); rows = blk*128 + (t>>4)*8 + i.
template<int NK4, int KROW, int COFF>
__device__ __forceinline__ void phaseB(const float* __restrict__ A0,
                                       int row0,
                                       const float4* __restrict__ W,
                                       int bg2,
                                       float acc[8][2]) {
  const float4* p[8];
  #pragma unroll
  for (int i = 0; i < 8; ++i) {
    int r = row0 + i; if (r >= M3) r = M3-1;
    p[i] = (const float4*)(A0 + (size_t)r*KROW);
  }
  float4 cur[8];
  #pragma unroll
  for (int i = 0; i < 8; ++i) cur[i] = p[i][0];
  #pragma unroll 1
  for (int s = 0; s < NK4; ++s) {
    float4 a[8];
    #pragma unroll
    for (int i = 0; i < 8; ++i) a[i] = cur[i];
    if (s + 1 < NK4) {
      #pragma unroll
      for (int i = 0; i < 8; ++i) cur[i] = p[i][s+1];
    }
    #pragma unroll
    for (int j = 0; j < 2; ++j) {
      float4 w = W[(size_t)(bg2 + j)*65 + COFF + s];
      #pragma unroll
      for (int i = 0; i < 8; ++i) {
        acc[i][j] = fmaf(a[i].x, w.x, fmaf(a[i].y, w.y,
                    fmaf(a[i].z, w.z, fmaf(a[i].w, w.w, acc[i][j]))));
      }
    }
  }
}

__global__ void __launch_bounds__(256) face3d_stageB(
    const float* __restrict__ idB, const float* __restrict__ exB,
    const float* __restrict__ texB, const float* __restrict__ meanshape,
    const float* __restrict__ meantex, const float* __restrict__ cpad,
    float* __restrict__ fs32, _Float16* __restrict__ fs16,
    float* __restrict__ texOut) {
  __shared__ float4 W[32*65];
  int t = threadIdx.x;
  {
    const float4* __restrict__ src = (const float4*)cpad;
    #pragma unroll
    for (int n = 0; n < 8; ++n) {
      int idx = t + 256*n;           // 0..2047
      int b = idx >> 6, k = idx & 63;
      W[b*65 + k] = src[idx];
    }
  }
  __syncthreads();
  int bg2 = (t & 15)*2;                       // batches bg2, bg2+1
  int row0 = blockIdx.x*128 + (t >> 4)*8;
  if (row0 >= M3) return;

  float acc[8][2];
  #pragma unroll
  for (int i=0;i<8;i++){acc[i][0]=0.f;acc[i][1]=0.f;}

  phaseB<20, 80, 0 >(idB, row0, W, bg2, acc);
  phaseB<16, 64, 20>(exB, row0, W, bg2, acc);

  #pragma unroll
  for (int i = 0; i < 8; ++i) {
    int r = row0 + i;
    if (r < M3) {
      float msv = meanshape[r];
      int v = r/3, c = r - 3*v;
      #pragma unroll
      for (int j = 0; j < 2; ++j) {
        int b = bg2 + j;
        float val = acc[i][j] + msv;
        fs32[(size_t)b*V4 + (size_t)v*4 + c] = val;
        fs16[((size_t)v*32 + b)*4 + c] = (_Float16)val;
      }
    }
  }

  #pragma unroll
  for (int i=0;i<8;i++){acc[i][0]=0.f;acc[i][1]=0.f;}

  phaseB<25, 100, 36>(texB, row0, W, bg2, acc);

  #pragma unroll
  for (int i = 0; i < 8; ++i) {
    int r = row0 + i;
    if (r < M3) {
      float mtv = meantex[r];
      #pragma unroll
      for (int j = 0; j < 2; ++j) {
        int b = bg2 + j;
        texOut[(size_t)b*M3 + r] = acc[i][j] + mtv;
      }
    }
  }
}

// ======================= Stage C: face normals (8 faces x 32 batches / block) =======================
__global__ void __launch_bounds__(256) face3d_stageC(
    const int* __restrict__ face_buf, const h4* __restrict__ fs16,
    h4* __restrict__ fn16) {
  int t = threadIdx.x;
  int b = t & 31;
  int f = blockIdx.x*8 + (t >> 5);
  if (f > N_FACE) return;
  if (f == N_FACE) {
    h4 z = {(_Float16)0, (_Float16)0, (_Float16)0, (_Float16)0};
    fn16[(size_t)f*32 + b] = z;
    return;
  }
  int i0 = face_buf[f*3+0];
  int i1 = face_buf[f*3+1];
  int i2 = face_buf[f*3+2];
  h4 q1 = fs16[(size_t)i0*32 + b];
  h4 q2 = fs16[(size_t)i1*32 + b];
  h4 q3 = fs16[(size_t)i2*32 + b];
  float e1x = (float)q1.x-(float)q2.x, e1y = (float)q1.y-(float)q2.y, e1z = (float)q1.z-(float)q2.z;
  float e2x = (float)q2.x-(float)q3.x, e2y = (float)q2.y-(float)q3.y, e2z = (float)q2.z-(float)q3.z;
  float nx = e1y*e2z - e1z*e2y;
  float ny = e1z*e2x - e1x*e2z;
  float nz = e1x*e2y - e1y*e2x;
  float inv = 1.0f / fmaxf(sqrtf(nx*nx + ny*ny + nz*nz), 1e-12f);
  h4 o = {(_Float16)(nx*inv), (_Float16)(ny*inv), (_Float16)(nz*inv), (_Float16)0};
  fn16[(size_t)f*32 + b] = o;
}

// ======================= Stage D: vertex normals + lighting + fst (+landmarks) =======================
__global__ void __launch_bounds__(256) face3d_stageD(
    const int* __restrict__ point_buf, const int* __restrict__ keypoints,
    const float* __restrict__ fs32, const h4* __restrict__ fn16,
    const float* __restrict__ rotAll, const float* __restrict__ treAll,
    const float* __restrict__ gAll, float* __restrict__ out) {
  const int mainBlocks = (N_VERT + 7)/8;   // 4464
  int bid = blockIdx.x;
  int t = threadIdx.x;
  if (bid < mainBlocks) {
    int b = t & 31;
    int v = bid*8 + (t >> 5);
    if (v >= N_VERT) return;
    const int4 pb0 = *(const int4*)(point_buf + (size_t)v*8);
    const int4 pb1 = *(const int4*)(point_buf + (size_t)v*8 + 4);
    h4 g0 = fn16[(size_t)pb0.x*32 + b];
    h4 g1 = fn16[(size_t)pb0.y*32 + b];
    h4 g2 = fn16[(size_t)pb0.z*32 + b];
    h4 g3 = fn16[(size_t)pb0.w*32 + b];
    h4 g4 = fn16[(size_t)pb1.x*32 + b];
    h4 g5 = fn16[(size_t)pb1.y*32 + b];
    h4 g6 = fn16[(size_t)pb1.z*32 + b];
    h4 g7 = fn16[(size_t)pb1.w*32 + b];
    float sx = ((float)g0.x+(float)g1.x)+((float)g2.x+(float)g3.x)
             + ((float)g4.x+(float)g5.x)+((float)g6.x+(float)g7.x);
    float sy = ((float)g0.y+(float)g1.y)+((float)g2.y+(float)g3.y)
             + ((float)g4.y+(float)g5.y)+((float)g6.y+(float)g7.y);
    float sz = ((float)g0.z+(float)g1.z)+((float)g2.z+(float)g3.z)
             + ((float)g4.z+(float)g5.z)+((float)g6.z+(float)g7.z);
    float inv = 1.0f / fmaxf(sqrtf(sx*sx + sy*sy + sz*sz), 1e-12f);
    float n0 = sx*inv, n1 = sy*inv, n2 = sz*inv;
    const float* rot = rotAll + b*9;
    float r00=rot[0], r01=rot[1], r02=rot[2];
    float r10=rot[3], r11=rot[4], r12=rot[5];
    float r20=rot[6], r21=rot[7], r22=rot[8];
    float nx = n0*r00 + n1*r10 + n2*r20;
    float ny = n0*r01 + n1*r11 + n2*r21;
    float nz = n0*r02 + n1*r12 + n2*r22;
    float Y1 = -A1C1*ny;
    float Y2 =  A1C1*nz;
    float Y3 = -A1C1*nx;
    float Y4 =  A2C2*nx*ny;
    float Y5 = -A2C2*ny*nz;
    float Y6 =  Y6C*(3.f*nz*nz - 1.f);
    float Y7 = -A2C2*nx*nz;
    float Y8 =  Y8C*(nx*nx - ny*ny);
    const float* g = gAll + b*27;
    float L0, L1, L2;
    {
      const float* gc = g;
      L0 = A0C0*gc[0] + Y1*gc[1] + Y2*gc[2] + Y3*gc[3] + Y4*gc[4]
         + Y5*gc[5] + Y6*gc[6] + Y7*gc[7] + Y8*gc[8];
      gc = g + 9;
      L1 = A0C0*gc[0] + Y1*gc[1] + Y2*gc[2] + Y3*gc[3] + Y4*gc[4]
         + Y5*gc[5] + Y6*gc[6] + Y7*gc[7] + Y8*gc[8];
      gc = g + 18;
      L2 = A0C0*gc[0] + Y1*gc[1] + Y2*gc[2] + Y3*gc[3] + Y4*gc[4]
         + Y5*gc[5] + Y6*gc[6] + Y7*gc[7] + Y8*gc[8];
    }
    float4 fsv = *(const float4*)(fs32 + (size_t)b*V4 + (size_t)v*4);
    const float* tre = treAll + b*3;
    float o0 = fsv.x*r00 + fsv.y*r10 + fsv.z*r20 + tre[0];
    float o1 = fsv.x*r01 + fsv.y*r11 + fsv.z*r21 + tre[1];
    float o2 = fsv.x*r02 + fsv.y*r12 + fsv.z*r22 + tre[2];
    size_t obase = (size_t)b*M3 + (size_t)v*3;
    out[FST_OFF + obase + 0] = o0;
    out[FST_OFF + obase + 1] = o1;
    out[FST_OFF + obase + 2] = o2;
    out[FC_OFF + obase + 0] = out[FC_OFF + obase + 0]*L0;
    out[FC_OFF + obase + 1] = out[FC_OFF + obase + 1]*L1;
    out[FC_OFF + obase + 2] = out[FC_OFF + obase + 2]*L2;
  } else {
    int idx = (bid - mainBlocks)*256 + t;
    if (idx >= NB*68) return;
    int b = idx & 31, j = idx >> 5;
    int kp = keypoints[j];
    const float* rot = rotAll + b*9;
    const float* tre = treAll + b*3;
    float4 fsv = *(const float4*)(fs32 + (size_t)b*V4 + (size_t)kp*4);
    float o0 = fsv.x*rot[0] + fsv.y*rot[3] + fsv.z*rot[6] + tre[0];
    float o1 = fsv.x*rot[1] + fsv.y*rot[4] + fsv.z*rot[7] + tre[1];
    float o2 = fsv.x*rot[2] + fsv.y*rot[5] + fsv.z*rot[8] + tre[2];
    float zc = 10.0f - o2;
    float axv = 1015.0f*o0 + 112.0f*zc;
    float ayv = 1015.0f*o1 + 112.0f*zc;
    out[LM_OFF + (size_t)b*136 + (size_t)j*2 + 0] = axv/zc;
    out[LM_OFF + (size_t)b*136 + (size_t)j*2 + 1] = ayv/zc;
  }
}

// ======================= launch =======================
extern "C" void kernel_launch(void* const* d_in, const int* in_sizes, int n_in,
                              void* d_out, int out_size, void* d_ws, size_t ws_size,
                              hipStream_t stream) {
  const float* coeff     = (const float*)d_in[0];
  const float* idB       = (const float*)d_in[1];
  const float* exB       = (const float*)d_in[2];
  const float* texB      = (const float*)d_in[3];
  const float* meanshape = (const float*)d_in[4];
  const float* meantex   = (const float*)d_in[5];
  const int*   face_buf  = (const int*)d_in[6];
  const int*   point_buf = (const int*)d_in[7];
  const int*   keypoints = (const int*)d_in[8];
  float* out = (float*)d_out;
  char*  wsb = (char*)d_ws;

  float*    fs32 = (float*)(wsb + WSB_FS32);
  _Float16* fs16 = (_Float16*)(wsb + WSB_FS16);
  h4*       fs16v= (h4*)(wsb + WSB_FS16);
  h4*       fn16 = (h4*)(wsb + WSB_FN16);
  float*    cpad = (float*)(wsb + WSB_CPAD);
  float*    rotW = (float*)(wsb + WSB_ROT);
  float*    treW = (float*)(wsb + WSB_TRE);
  float*    gW   = (float*)(wsb + WSB_G);
  float*    mean = (float*)(wsb + WSB_MEAN);

  (void)hipMemsetAsync(mean, 0, 3*sizeof(float), stream);

  hipLaunchKernelGGL(face3d_stageA1, dim3(56), dim3(256), 0, stream, meanshape, mean);
  hipLaunchKernelGGL(face3d_stageA2, dim3(1), dim3(256), 0, stream,
                     coeff, mean, cpad, rotW, treW, gW);

  int gridB = (M3 + 127)/128;            // 837
  hipLaunchKernelGGL(face3d_stageB, dim3(gridB), dim3(256), 0, stream,
                     idB, exB, texB, meanshape, meantex,
                     cpad, fs32, fs16, out + FC_OFF);

  int gridC = (N_FACE + 1 + 7)/8;        // 8849
  hipLaunchKernelGGL(face3d_stageC, dim3(gridC), dim3(256), 0, stream,
                     face_buf, fs16v, fn16);

  int mainBlocks = (N_VERT + 7)/8;       // 4464
  int lmBlocks   = (NB*68 + 255)/256;    // 9
  hipLaunchKernelGGL(face3d_stageD, dim3(mainBlocks + lmBlocks), dim3(256), 0, stream,
                     point_buf, keypoints, fs32, fn16,
                     rotW, treW, gW, out);
}